// Round 1
// 294.562 us; speedup vs baseline: 1.0796x; 1.0796x over previous
//
#include <hip/hip_runtime.h>
#include <hip/hip_bf16.h>

#define NB   8
#define CCH  256
#define KCH  128
#define SSP  4096

typedef unsigned short u16;
typedef __attribute__((ext_vector_type(8))) short  bfrag;  // 8 bf16 = 4 VGPRs
typedef __attribute__((ext_vector_type(4))) float  ffrag;  // 4 fp32 acc

#define MFMA16(a, b, c) __builtin_amdgcn_mfma_f32_16x16x32_bf16((a), (b), (c), 0, 0, 0)
// u16-index XOR swizzle: flips bits 3-5 (16B granule) by row&7 -> bank spread
#define SWZ(i, r) ((unsigned)(i) ^ ((((unsigned)(r)) & 7u) << 3))

__device__ __forceinline__ u16 f2b(float f) {            // fp32 -> bf16 RNE
    union { float f; unsigned u; } v; v.f = f;
    return (u16)((v.u + 0x7fffu + ((v.u >> 16) & 1u)) >> 16);
}

// ---------------------------------------------------------------------------
// K1: g and phi projections, MFMA, register-pipelined staging.
// 1D grid 512 (2 blocks/CU), block 256 (4 waves). n = bid&7 pins each batch
// to one XCD (x[n] = 4MB fits that XCD's L2).
// G is written TRANSPOSED: [N, K, S]; P stays [N, S, K].
// ---------------------------------------------------------------------------
__global__ __launch_bounds__(256, 2) void proj_gp_kernel(
    const float* __restrict__ x,
    const float* __restrict__ Wg, const float* __restrict__ bg,
    const float* __restrict__ Wp, const float* __restrict__ bp,
    u16* __restrict__ G,   // [N,K,S] transposed
    u16* __restrict__ P)   // [N,S,K]
{
    __shared__ __align__(16) u16 sm[12800];
    const int tid  = threadIdx.x;
    const int wv   = tid >> 6;
    const int lane = tid & 63;
    const int quad = lane >> 4, l16 = lane & 15;
    const int bid  = blockIdx.x;
    const int n  = bid & 7;
    const int s0 = (bid >> 3) * 64;

    const ffrag zf = {0.f, 0.f, 0.f, 0.f};
    ffrag ga[8], pa[8];
#pragma unroll
    for (int kb = 0; kb < 8; kb++) { ga[kb] = zf; pa[kb] = zf; }

    // ---- pipeline registers: preload chunk c0=0 ----
    float4 xreg[2], wgreg[4], wpreg[4];
#pragma unroll
    for (int i = 0; i < 2; i++) {
        int f = tid + i * 256;
        int c = f >> 4, s4 = (f & 15) * 4;
        xreg[i] = *(const float4*)&x[((size_t)n * CCH + c) * SSP + s0 + s4];
    }
#pragma unroll
    for (int i = 0; i < 4; i++) {
        int f = tid + i * 256;
        int k = f >> 3, co = (f & 7) * 4;
        wgreg[i] = *(const float4*)&Wg[k * CCH + co];
        wpreg[i] = *(const float4*)&Wp[k * CCH + co];
    }

    for (int c0 = 0; c0 < CCH; c0 += 32) {
        __syncthreads();
#pragma unroll
        for (int i = 0; i < 2; i++) {
            int f = tid + i * 256;
            int c = f >> 4, s4 = (f & 15) * 4;
            sm[(s4 + 0) * 40 + c] = f2b(xreg[i].x);
            sm[(s4 + 1) * 40 + c] = f2b(xreg[i].y);
            sm[(s4 + 2) * 40 + c] = f2b(xreg[i].z);
            sm[(s4 + 3) * 40 + c] = f2b(xreg[i].w);
        }
#pragma unroll
        for (int i = 0; i < 4; i++) {
            int f = tid + i * 256;
            int k = f >> 3, co = (f & 7) * 4;
            ushort4 g4 = {f2b(wgreg[i].x), f2b(wgreg[i].y), f2b(wgreg[i].z), f2b(wgreg[i].w)};
            ushort4 p4 = {f2b(wpreg[i].x), f2b(wpreg[i].y), f2b(wpreg[i].z), f2b(wpreg[i].w)};
            *(ushort4*)&sm[2560 + k * 40 + co] = g4;
            *(ushort4*)&sm[7680 + k * 40 + co] = p4;
        }
        if (c0 + 32 < CCH) {
#pragma unroll
            for (int i = 0; i < 2; i++) {
                int f = tid + i * 256;
                int c = f >> 4, s4 = (f & 15) * 4;
                xreg[i] = *(const float4*)&x[((size_t)n * CCH + c0 + 32 + c) * SSP + s0 + s4];
            }
#pragma unroll
            for (int i = 0; i < 4; i++) {
                int f = tid + i * 256;
                int k = f >> 3, co = (f & 7) * 4;
                wgreg[i] = *(const float4*)&Wg[k * CCH + c0 + 32 + co];
                wpreg[i] = *(const float4*)&Wp[k * CCH + c0 + 32 + co];
            }
        }
        __syncthreads();
        bfrag a = *(const bfrag*)&sm[(16 * wv + l16) * 40 + quad * 8];
#pragma unroll
        for (int kb = 0; kb < 8; kb++) {
            bfrag bgf = *(const bfrag*)&sm[2560 + (16 * kb + l16) * 40 + quad * 8];
            bfrag bpf = *(const bfrag*)&sm[7680 + (16 * kb + l16) * 40 + quad * 8];
            ga[kb] = MFMA16(a, bgf, ga[kb]);
            pa[kb] = MFMA16(a, bpf, pa[kb]);
        }
    }
#pragma unroll
    for (int kb = 0; kb < 8; kb++) {
        int k = l16 + 16 * kb;
        float bgv = bg[k], bpv = bp[k];
        int srow = s0 + 16 * wv + quad * 4;
        ushort4 g4 = {f2b(ga[kb][0] + bgv), f2b(ga[kb][1] + bgv),
                      f2b(ga[kb][2] + bgv), f2b(ga[kb][3] + bgv)};
        *(ushort4*)&G[(size_t)n * KCH * SSP + (size_t)k * SSP + srow] = g4;
#pragma unroll
        for (int r = 0; r < 4; r++)
            P[((size_t)n * SSP + srow + r) * KCH + k] = f2b(pa[kb][r] + bpv);
    }
}

// ---------------------------------------------------------------------------
// K2: fused theta-proj + flash attention + out-proj, all MFMA.
// Round-6 changes vs round 5 (latency-bound fix: 10.9% occupancy, 23% of
// cycles in LDS bank conflicts):
//  - 512-thread blocks (8 waves): 2 waves/SIMD instead of 1; each wave owns
//    16 q-rows (qb dim dropped). Grid stays 256 = 1 block/CU.
//  - LDS 104 KB -> 64 KB: PS aliased into dead QS region during t-loop; Wo
//    staged per-128-row half in the KS/GT region; all pads removed.
//  - Uniform XOR swizzle (idx ^= (row&7)<<3 in u16) on QS/YS/KS/GT/PS/WO:
//    bank-conflict-free b128 frag reads at power-of-2 strides.
//  - XCD-affinity: n = bid&7 -> each XCD's L2 caches one batch's P+G (2MB).
//  - log2e folded into Q scale; exp via v_exp_f32 (exp2) directly.
// LDS map (u16 idx): [0,16384) QS(ph0) / PS(t-loop, [0,8192)) / YS(epi)
//                    [16384,32768) XT+WT(ph0) / KS+GT(t-loop) / WO(epi)
// ---------------------------------------------------------------------------
__global__ __launch_bounds__(512, 2) void attn_fused_kernel(
    const float* __restrict__ x,
    const float* __restrict__ Wt, const float* __restrict__ bt,
    const u16* __restrict__ Pb,   // phi rows bf16 [N,S,K]
    const u16* __restrict__ Gt,   // g bf16 TRANSPOSED [N,K,S]
    const float* __restrict__ Wo, const float* __restrict__ bo,
    float* __restrict__ out)
{
    __shared__ __align__(16) u16 sm[32768];     // 64 KB
    const int tid  = threadIdx.x;
    const int wv   = tid >> 6;                  // 0..7
    const int lane = tid & 63;
    const int quad = lane >> 4, l16 = lane & 15;
    const int bid  = blockIdx.x;
    const int n    = bid & 7;
    const int q0   = (bid >> 3) * 128;
    // 1/sqrt(128) * log2(e): exp(s*scale) == exp2(s*qscale)
    const float qscale = 0.08838834764831845f * 1.4426950408889634f;
    const ffrag zf = {0.f, 0.f, 0.f, 0.f};

    const int XTb = 16384, WTb = 21504, KSb = 16384, GTb = 24576, WOb = 16384;

    const u16* Pbase = Pb + (size_t)n * SSP * KCH;
    const u16* Gbase = Gt + (size_t)n * KCH * SSP;

    // ---- issue first K/G tile loads NOW; they complete during phase 0 ----
    uint4 kreg[2], greg[2];
    {
        const uint4* Pg = (const uint4*)Pbase;
#pragma unroll
        for (int i = 0; i < 2; i++) kreg[i] = Pg[tid + i * 512];
#pragma unroll
        for (int i = 0; i < 2; i++) {
            int f = tid + i * 512;
            int k = f >> 3, ch = f & 7;
            greg[i] = ((const uint4*)(Gbase + (size_t)k * SSP))[ch];
        }
    }

    // ---------------- Phase 0: Qs = (theta(x)+bt)*qscale, bf16 ----------------
    {
        ffrag qa[8];
#pragma unroll
        for (int kb = 0; kb < 8; kb++) qa[kb] = zf;

        for (int c0 = 0; c0 < CCH; c0 += 32) {
#pragma unroll
            for (int i = 0; i < 2; i++) {
                int f = tid + i * 512;
                int c = f >> 5, s4 = (f & 31) * 4;
                float4 xv = *(const float4*)&x[((size_t)n * CCH + c0 + c) * SSP + q0 + s4];
                sm[XTb + (s4 + 0) * 40 + c] = f2b(xv.x);
                sm[XTb + (s4 + 1) * 40 + c] = f2b(xv.y);
                sm[XTb + (s4 + 2) * 40 + c] = f2b(xv.z);
                sm[XTb + (s4 + 3) * 40 + c] = f2b(xv.w);
            }
#pragma unroll
            for (int i = 0; i < 2; i++) {
                int f = tid + i * 512;
                int k = f >> 3, co = (f & 7) * 4;
                float4 wq = *(const float4*)&Wt[k * CCH + c0 + co];
                ushort4 q4 = {f2b(wq.x), f2b(wq.y), f2b(wq.z), f2b(wq.w)};
                *(ushort4*)&sm[WTb + k * 40 + co] = q4;
            }
            __syncthreads();
            bfrag aq = *(const bfrag*)&sm[XTb + (16 * wv + l16) * 40 + quad * 8];
#pragma unroll
            for (int kb = 0; kb < 8; kb++) {
                bfrag bw = *(const bfrag*)&sm[WTb + (16 * kb + l16) * 40 + quad * 8];
                qa[kb] = MFMA16(aq, bw, qa[kb]);
            }
            __syncthreads();
        }
#pragma unroll
        for (int kb = 0; kb < 8; kb++) {
            float btv = bt[l16 + 16 * kb];
#pragma unroll
            for (int r = 0; r < 4; r++) {
                int row = 16 * wv + quad * 4 + r;
                sm[SWZ(row * 128 + l16 + 16 * kb, row)] = f2b((qa[kb][r] + btv) * qscale);
            }
        }
        // QS rows are wave-private; in-wave LDS ordering suffices below.
    }

    // ---- hoist Q A-fragments into registers (read own rows, no barrier) ----
    bfrag qf[4];
#pragma unroll
    for (int kc = 0; kc < 4; kc++)
        qf[kc] = *(const bfrag*)&sm[SWZ((16 * wv + l16) * 128 + kc * 32 + quad * 8, l16)];

    // ---------------- Phase 1: flash attention over t-tiles ----------------
    ffrag O[8];
#pragma unroll
    for (int kb = 0; kb < 8; kb++) O[kb] = zf;
    float l_r[4] = {0.f, 0.f, 0.f, 0.f};

    for (int t0 = 0; t0 < SSP; t0 += 64) {
        __syncthreads();                    // previous tile fully consumed
        // ---- commit pipelined tile to LDS (swizzled) ----
#pragma unroll
        for (int i = 0; i < 2; i++) {
            int f = tid + i * 512;
            int row = f >> 4, c8 = (f & 15) * 8;
            *(uint4*)&sm[KSb + SWZ(row * 128 + c8, row)] = kreg[i];
        }
#pragma unroll
        for (int i = 0; i < 2; i++) {
            int f = tid + i * 512;
            int k = f >> 3, ch = f & 7;
            *(uint4*)&sm[GTb + SWZ(k * 64 + ch * 8, k)] = greg[i];
        }
        // ---- prefetch next tile (in flight across the whole compute) ----
        if (t0 + 64 < SSP) {
            const uint4* Pg = (const uint4*)(Pbase + (size_t)(t0 + 64) * KCH);
#pragma unroll
            for (int i = 0; i < 2; i++) kreg[i] = Pg[tid + i * 512];
#pragma unroll
            for (int i = 0; i < 2; i++) {
                int f = tid + i * 512;
                int k = f >> 3, ch = f & 7;
                greg[i] = ((const uint4*)(Gbase + (size_t)k * SSP + t0 + 64))[ch];
            }
        }
        __syncthreads();                    // staging visible

        // ---- QK^T (Q from registers) ----
        ffrag sa[4];
#pragma unroll
        for (int tb = 0; tb < 4; tb++) sa[tb] = zf;
#pragma unroll
        for (int kc = 0; kc < 4; kc++)
#pragma unroll
            for (int tb = 0; tb < 4; tb++) {
                bfrag bk = *(const bfrag*)&sm[KSb + SWZ((16 * tb + l16) * 128 + kc * 32 + quad * 8, l16)];
                sa[tb] = MFMA16(qf[kc], bk, sa[tb]);
            }

        // ---- softmax numerator; l accumulated per-lane ----
#pragma unroll
        for (int r = 0; r < 4; r++) {
            float p0 = __builtin_amdgcn_exp2f(sa[0][r]);
            float p1 = __builtin_amdgcn_exp2f(sa[1][r]);
            float p2 = __builtin_amdgcn_exp2f(sa[2][r]);
            float p3 = __builtin_amdgcn_exp2f(sa[3][r]);
            l_r[r] += (p0 + p1) + (p2 + p3);
            int row = 16 * wv + quad * 4 + r;
            int rb = row * 64 + l16;
            sm[SWZ(rb +  0, row)] = f2b(p0);
            sm[SWZ(rb + 16, row)] = f2b(p1);
            sm[SWZ(rb + 32, row)] = f2b(p2);
            sm[SWZ(rb + 48, row)] = f2b(p3);
        }
        // PS rows are wave-private: in-wave LDS ordering, no barrier needed.

        // ---- PV: O += P * G ----
#pragma unroll
        for (int tc = 0; tc < 2; tc++) {
            bfrag ap = *(const bfrag*)&sm[SWZ((16 * wv + l16) * 64 + tc * 32 + quad * 8, l16)];
#pragma unroll
            for (int kb = 0; kb < 8; kb++) {
                bfrag bg = *(const bfrag*)&sm[GTb + SWZ((16 * kb + l16) * 64 + tc * 32 + quad * 8, l16)];
                O[kb] = MFMA16(ap, bg, O[kb]);
            }
        }
    }

    __syncthreads();    // all PV done: YS (stride 128) overlaps other waves' PS

    // ---------------- Phase 2: reduce l; y -> YS; out = x + Wo*y + bo ----
#pragma unroll
    for (int r = 0; r < 4; r++) {
        float rs = l_r[r];
#pragma unroll
        for (int m = 1; m <= 8; m <<= 1) rs += __shfl_xor(rs, m);
        l_r[r] = 1.0f / rs;
    }
#pragma unroll
    for (int kb = 0; kb < 8; kb++)
#pragma unroll
        for (int r = 0; r < 4; r++) {
            int row = 16 * wv + quad * 4 + r;
            sm[SWZ(row * 128 + l16 + 16 * kb, row)] = f2b(O[kb][r] * l_r[r]);
        }

#pragma unroll
    for (int half = 0; half < 2; half++) {
        __syncthreads();    // half0: region B free; half1: prev Wo reads done
        // stage Wo rows [half*128, half*128+128) bf16, swizzled [128][128]
#pragma unroll
        for (int i = 0; i < 8; i++) {
            int f = tid + i * 512;
            int c = f >> 5, ko = (f & 31) * 4;
            float4 w = *(const float4*)&Wo[(size_t)(half * 128 + c) * KCH + ko];
            ushort4 w4 = {f2b(w.x), f2b(w.y), f2b(w.z), f2b(w.w)};
            *(ushort4*)&sm[WOb + SWZ(c * 128 + ko, c)] = w4;
        }
        __syncthreads();

        ffrag zc[8];
#pragma unroll
        for (int cb = 0; cb < 8; cb++) zc[cb] = zf;
#pragma unroll
        for (int kc = 0; kc < 4; kc++) {
            bfrag ay = *(const bfrag*)&sm[SWZ((16 * wv + l16) * 128 + kc * 32 + quad * 8, l16)];
#pragma unroll
            for (int cb = 0; cb < 8; cb++) {
                bfrag bw = *(const bfrag*)&sm[WOb + SWZ((16 * cb + l16) * 128 + kc * 32 + quad * 8, l16)];
                zc[cb] = MFMA16(ay, bw, zc[cb]);
            }
        }
#pragma unroll
        for (int cb = 0; cb < 8; cb++) {
            int c = half * 128 + 16 * cb + l16;
            float bc = bo[c];
            size_t base = ((size_t)n * CCH + c) * SSP + q0 + 16 * wv + quad * 4;
            float4 xv = *(const float4*)&x[base];
            float4 ov;
            ov.x = xv.x + zc[cb][0] + bc;
            ov.y = xv.y + zc[cb][1] + bc;
            ov.z = xv.z + zc[cb][2] + bc;
            ov.w = xv.w + zc[cb][3] + bc;
            *(float4*)&out[base] = ov;
        }
    }
}

// ---------------------------------------------------------------------------
extern "C" void kernel_launch(void* const* d_in, const int* in_sizes, int n_in,
                              void* d_out, int out_size, void* d_ws, size_t ws_size,
                              hipStream_t stream) {
    const float* x  = (const float*)d_in[0];
    const float* Wg = (const float*)d_in[1];
    const float* bg = (const float*)d_in[2];
    const float* Wt = (const float*)d_in[3];
    const float* bt = (const float*)d_in[4];
    const float* Wp = (const float*)d_in[5];
    const float* bp = (const float*)d_in[6];
    const float* Wo = (const float*)d_in[7];
    const float* bo = (const float*)d_in[8];
    float* out = (float*)d_out;

    // ws: 16 MB total (verified-safe): G^T bf16 8MB + P bf16 8MB.
    u16* G = (u16*)d_ws;                       // [N,K,S] transposed
    u16* P = G + (size_t)NB * SSP * KCH;       // [N,S,K]

    proj_gp_kernel<<<dim3(NB * SSP / 64), 256, 0, stream>>>(x, Wg, bg, Wp, bp, G, P);
    attn_fused_kernel<<<dim3(NB * SSP / 128), 512, 0, stream>>>(x, Wt, bt, P, G, Wo, bo, out);
}